// Round 6
// baseline (12.181 us; speedup 1.0000x reference)
//
#include <hip/hip_runtime.h>

#define EPS 1e-5f

// Geometry: inp (25,2,128,8,8) fp32 -> rows R = g*2+c of Y (6400 x 64), g=(n,s).
// InstanceNorm over row pairs {2g,2g+1}; QKV = Y @ qkv_w^T + b (192 cols);
// c=2 collapses linear attn to 2x2 M = q k^T, attn = v + M v;
// OUT = attn @ proj_w^T + proj_b + inp.  Output fp32.
//
// R6: 400 blocks x 64 threads (ONE wave, 16 rows = 8 instances).
//  - B-fragments loaded DIRECTLY global->reg in mfma layout (no weight LDS,
//    no staging barrier): lane reads w[(nt*16+lr)*64 + k*32 + lg*8..+8), cvt f16.
//    Weights (64 KB) are L2/L3-resident across all 400 waves.
//  - InstanceNorm in fragment layout (butterfly xor 1,16,32), A-frags born in regs.
//  - Only LDS: 2 KB attn bounce (C-layout -> A-layout), one wave-local barrier.
//  - proj B-frags prefetched before the M-reduce to hide their latency.

typedef _Float16 half8 __attribute__((ext_vector_type(8)));
typedef float    f32x4 __attribute__((ext_vector_type(4)));

__device__ __forceinline__ half8 cvt8(float4 a, float4 b) {
    half8 h;
    h[0] = (_Float16)a.x; h[1] = (_Float16)a.y; h[2] = (_Float16)a.z; h[3] = (_Float16)a.w;
    h[4] = (_Float16)b.x; h[5] = (_Float16)b.y; h[6] = (_Float16)b.z; h[7] = (_Float16)b.w;
    return h;
}

// byte offset into a 64-f16-wide (128 B stride) LDS tile, 16B-chunk XOR swizzle
__device__ __forceinline__ int swz(int row, int colByte) {
    return row * 128 + (colByte ^ ((row & 7) << 4));
}

__global__ __launch_bounds__(64)
void attn_mfma(const float* __restrict__ inp,
               const float* __restrict__ qkv_w,
               const float* __restrict__ qkv_b,
               const float* __restrict__ proj_w,
               const float* __restrict__ proj_b,
               float* __restrict__ out)
{
    __shared__ _Float16 a_lds[16 * 64];   // attn bounce tile (2 KB), swizzled

    const int l  = threadIdx.x;
    const int lr = l & 15;          // fragment row / output-col index
    const int lg = l >> 4;          // k-group (0..3)

    // lane's Y-row (A-side): R = blk*16 + lr
    const int R = blockIdx.x * 16 + lr;
    const int g = R >> 1, c = R & 1;
    const int n = g >> 7, s = g & 127;
    const int rowbase = n * 16384 + c * 8192 + s * 64;   // float idx of row start
    const int col0 = lg * 8;

    // ---------------- inp loads (A-fragment span) ----------------
    const float4 x0a = *reinterpret_cast<const float4*>(inp + rowbase + col0);
    const float4 x0b = *reinterpret_cast<const float4*>(inp + rowbase + col0 + 4);
    const float4 x1a = *reinterpret_cast<const float4*>(inp + rowbase + col0 + 32);
    const float4 x1b = *reinterpret_cast<const float4*>(inp + rowbase + col0 + 36);

    // ---------------- GEMM2 B-frags: prefetch proj_w now (latency hides) ----------------
    half8 pw0[4], pw1[4];
    #pragma unroll
    for (int nt = 0; nt < 4; ++nt) {
        const float* pb = proj_w + (nt * 16 + lr) * 64 + lg * 8;
        pw0[nt] = cvt8(*reinterpret_cast<const float4*>(pb),
                       *reinterpret_cast<const float4*>(pb + 4));
        pw1[nt] = cvt8(*reinterpret_cast<const float4*>(pb + 32),
                       *reinterpret_cast<const float4*>(pb + 36));
    }

    // ---------------- InstanceNorm in fragment layout ----------------
    float s1 = (x0a.x + x0a.y) + (x0a.z + x0a.w) + (x0b.x + x0b.y) + (x0b.z + x0b.w)
             + (x1a.x + x1a.y) + (x1a.z + x1a.w) + (x1b.x + x1b.y) + (x1b.z + x1b.w);
    float s2 = x0a.x*x0a.x + x0a.y*x0a.y + x0a.z*x0a.z + x0a.w*x0a.w
             + x0b.x*x0b.x + x0b.y*x0b.y + x0b.z*x0b.z + x0b.w*x0b.w
             + x1a.x*x1a.x + x1a.y*x1a.y + x1a.z*x1a.z + x1a.w*x1a.w
             + x1b.x*x1b.x + x1b.y*x1b.y + x1b.z*x1b.z + x1b.w*x1b.w;
    // rows {2g,2g+1} = lr xor 1; k-groups = lane xor 16, 32  -> instance's 128 values
    s1 += __shfl_xor(s1, 1);  s2 += __shfl_xor(s2, 1);
    s1 += __shfl_xor(s1, 16); s2 += __shfl_xor(s2, 16);
    s1 += __shfl_xor(s1, 32); s2 += __shfl_xor(s2, 32);
    const float mean = s1 * (1.0f / 128.0f);
    const float var  = s2 * (1.0f / 128.0f) - mean * mean;   // biased, like jnp.var
    const float rs   = rsqrtf(var + EPS);

    half8 a0, a1;
    a0[0]=(_Float16)((x0a.x-mean)*rs); a0[1]=(_Float16)((x0a.y-mean)*rs);
    a0[2]=(_Float16)((x0a.z-mean)*rs); a0[3]=(_Float16)((x0a.w-mean)*rs);
    a0[4]=(_Float16)((x0b.x-mean)*rs); a0[5]=(_Float16)((x0b.y-mean)*rs);
    a0[6]=(_Float16)((x0b.z-mean)*rs); a0[7]=(_Float16)((x0b.w-mean)*rs);
    a1[0]=(_Float16)((x1a.x-mean)*rs); a1[1]=(_Float16)((x1a.y-mean)*rs);
    a1[2]=(_Float16)((x1a.z-mean)*rs); a1[3]=(_Float16)((x1a.w-mean)*rs);
    a1[4]=(_Float16)((x1b.x-mean)*rs); a1[5]=(_Float16)((x1b.y-mean)*rs);
    a1[6]=(_Float16)((x1b.z-mean)*rs); a1[7]=(_Float16)((x1b.w-mean)*rs);

    // ---------------- GEMM1: 12 N-tiles, B-frags straight from global ----------------
    f32x4 acc[12];
    #pragma unroll
    for (int nt = 0; nt < 12; ++nt) acc[nt] = f32x4{0.f, 0.f, 0.f, 0.f};
    #pragma unroll
    for (int nt = 0; nt < 12; ++nt) {
        const float* wb = qkv_w + (nt * 16 + lr) * 64 + lg * 8;
        const half8 b0 = cvt8(*reinterpret_cast<const float4*>(wb),
                              *reinterpret_cast<const float4*>(wb + 4));
        const half8 b1 = cvt8(*reinterpret_cast<const float4*>(wb + 32),
                              *reinterpret_cast<const float4*>(wb + 36));
        acc[nt] = __builtin_amdgcn_mfma_f32_16x16x32_f16(a0, b0, acc[nt], 0, 0, 0);
        acc[nt] = __builtin_amdgcn_mfma_f32_16x16x32_f16(a1, b1, acc[nt], 0, 0, 0);
    }
    #pragma unroll
    for (int nt = 0; nt < 12; ++nt) {
        const float b = qkv_b[nt * 16 + lr];
        acc[nt].x += b; acc[nt].y += b; acc[nt].z += b; acc[nt].w += b;
    }

    // ---------------- 2x2 M per instance + attn (C-layout registers) ----------------
    // lane holds cols o=nt*16+lr of rows m = lg*4 + r; rows r{0,1}=instance A, r{2,3}=B
    float p[8] = {0.f,0.f,0.f,0.f,0.f,0.f,0.f,0.f};
    #pragma unroll
    for (int nt = 0; nt < 4; ++nt) {
        const f32x4 q = acc[nt], k = acc[4 + nt];
        p[0] = fmaf(q.x, k.x, p[0]);  p[1] = fmaf(q.x, k.y, p[1]);
        p[2] = fmaf(q.y, k.x, p[2]);  p[3] = fmaf(q.y, k.y, p[3]);
        p[4] = fmaf(q.z, k.z, p[4]);  p[5] = fmaf(q.z, k.w, p[5]);
        p[6] = fmaf(q.w, k.z, p[6]);  p[7] = fmaf(q.w, k.w, p[7]);
    }
    #pragma unroll
    for (int m = 8; m >= 1; m >>= 1) {    // reduce 64 cols: 16 lanes (lr) x 4 nt
        #pragma unroll
        for (int z = 0; z < 8; ++z) p[z] += __shfl_xor(p[z], m);
    }
    #pragma unroll
    for (int nt = 0; nt < 4; ++nt) {
        const f32x4 v = acc[8 + nt];
        float av[4];
        av[0] = v.x + fmaf(p[0], v.x, p[1] * v.y);
        av[1] = v.y + fmaf(p[2], v.x, p[3] * v.y);
        av[2] = v.z + fmaf(p[4], v.z, p[5] * v.w);
        av[3] = v.w + fmaf(p[6], v.z, p[7] * v.w);
        #pragma unroll
        for (int r = 0; r < 4; ++r) {
            const int row  = lg * 4 + r;
            const int colB = (nt * 16 + lr) * 2;
            *reinterpret_cast<_Float16*>(
                reinterpret_cast<char*>(a_lds) + swz(row, colB)) = (_Float16)av[r];
        }
    }
    __syncthreads();   // single-wave: compiles to lgkmcnt wait (+cheap barrier)

    // ---------------- GEMM2: attn @ proj^T (B-frags already in regs) ----------------
    const half8 a20 = *reinterpret_cast<const half8*>(
        reinterpret_cast<const char*>(a_lds) + swz(lr, lg * 16));
    const half8 a21 = *reinterpret_cast<const half8*>(
        reinterpret_cast<const char*>(a_lds) + swz(lr, lg * 16 + 64));
    f32x4 acc2[4];
    #pragma unroll
    for (int nt = 0; nt < 4; ++nt) acc2[nt] = f32x4{0.f, 0.f, 0.f, 0.f};
    #pragma unroll
    for (int nt = 0; nt < 4; ++nt) {
        acc2[nt] = __builtin_amdgcn_mfma_f32_16x16x32_f16(a20, pw0[nt], acc2[nt], 0, 0, 0);
        acc2[nt] = __builtin_amdgcn_mfma_f32_16x16x32_f16(a21, pw1[nt], acc2[nt], 0, 0, 0);
    }

    // ---------------- epilogue: + proj_b + residual, fp32 store ----------------
    #pragma unroll
    for (int nt = 0; nt < 4; ++nt) {
        const int col = nt * 16 + lr;
        const float pb = proj_b[col];
        #pragma unroll
        for (int r = 0; r < 4; ++r) {
            const int Rg = blockIdx.x * 16 + lg * 4 + r;
            const int gi = Rg >> 1, cc = Rg & 1;
            const int nn = gi >> 7, ss = gi & 127;
            const int addr = nn * 16384 + cc * 8192 + ss * 64 + col;
            const float a = (r == 0) ? acc2[nt].x : (r == 1) ? acc2[nt].y
                          : (r == 2) ? acc2[nt].z : acc2[nt].w;
            out[addr] = a + pb + inp[addr];
        }
    }
}

extern "C" void kernel_launch(void* const* d_in, const int* in_sizes, int n_in,
                              void* d_out, int out_size, void* d_ws, size_t ws_size,
                              hipStream_t stream) {
    const float* inp    = (const float*)d_in[0];
    const float* qkv_w  = (const float*)d_in[1];
    const float* qkv_b  = (const float*)d_in[2];
    const float* proj_w = (const float*)d_in[3];
    const float* proj_b = (const float*)d_in[4];
    float* out = (float*)d_out;

    // 6400 rows / 16 per wave = 400 single-wave blocks
    attn_mfma<<<dim3(400), dim3(64), 0, stream>>>(inp, qkv_w, qkv_b, proj_w, proj_b, out);
}

// Round 7
// 9.985 us; speedup vs baseline: 1.2200x; 1.2200x over previous
//
#include <hip/hip_runtime.h>

#define EPS 1e-5f

// Geometry: inp (25,2,128,8,8) fp32 -> rows R = g*2+c of Y (6400 x 64), g=(n,s).
// InstanceNorm over row pairs {2g,2g+1}; QKV = Y @ qkv_w^T + b (192 cols);
// c=2 collapses linear attn to 2x2 M = q k^T, attn = v + M v;
// OUT = attn @ proj_w^T + proj_b + inp.  Output fp32.
//
// R7 = R5 structure (best: 9.88 us) minus proj staging, with widened qkv staging.
// 200 blocks x 128 threads (2 waves, 32 rows = 16 instances; wave w -> M-tile w).
//  - qkv_w: coalesced fp32 loads (32 B/thread/iter), cvt f16, ds_write_b128
//    into XOR-swizzled LDS (16 B granularity matches swizzle).
//  - proj_w (16 KB, L2-resident): direct global->reg fragment prefetch, early.
//  - InstanceNorm in MFMA fragment layout (butterfly xor 1,16,32).
//  - mfma_f32_16x16x32_f16; 2x2 M from C-layout regs; 4 KB attn LDS bounce.

typedef _Float16 half8 __attribute__((ext_vector_type(8)));
typedef float    f32x4 __attribute__((ext_vector_type(4)));

__device__ __forceinline__ half8 cvt8(float4 a, float4 b) {
    half8 h;
    h[0] = (_Float16)a.x; h[1] = (_Float16)a.y; h[2] = (_Float16)a.z; h[3] = (_Float16)a.w;
    h[4] = (_Float16)b.x; h[5] = (_Float16)b.y; h[6] = (_Float16)b.z; h[7] = (_Float16)b.w;
    return h;
}

// byte offset into a 64-f16-wide (128 B stride) LDS tile, 16B-chunk XOR swizzle
__device__ __forceinline__ int swz(int row, int colByte) {
    return row * 128 + (colByte ^ ((row & 7) << 4));
}

__global__ __launch_bounds__(128)
void attn_mfma(const float* __restrict__ inp,
               const float* __restrict__ qkv_w,
               const float* __restrict__ qkv_b,
               const float* __restrict__ proj_w,
               const float* __restrict__ proj_b,
               float* __restrict__ out)
{
    __shared__ __align__(16) _Float16 w_lds[192 * 64];   // qkv_w f16, swizzled (24 KB)
    __shared__ __align__(16) _Float16 a_lds[32 * 64];    // attn bounce (4 KB), swizzled

    const int tid = threadIdx.x;
    const int w   = tid >> 6;       // wave id = M-tile
    const int l   = tid & 63;
    const int lr  = l & 15;         // fragment row / output-col index
    const int lg  = l >> 4;         // k-group (0..3)

    // lane's Y-row (A-side): R = blk*32 + w*16 + lr
    const int lrow = (w << 4) | lr;
    const int R = blockIdx.x * 32 + lrow;
    const int g = R >> 1, c = R & 1;
    const int n = g >> 7, s = g & 127;
    const int rowbase = n * 16384 + c * 8192 + s * 64;
    const int col0 = lg * 8;

    // ---------------- inp loads (A-fragment span) ----------------
    const float4 x0a = *reinterpret_cast<const float4*>(inp + rowbase + col0);
    const float4 x0b = *reinterpret_cast<const float4*>(inp + rowbase + col0 + 4);
    const float4 x1a = *reinterpret_cast<const float4*>(inp + rowbase + col0 + 32);
    const float4 x1b = *reinterpret_cast<const float4*>(inp + rowbase + col0 + 36);

    // ---------------- stage qkv_w: coalesced fp32 -> f16 LDS (swizzled) ----------------
    // 12288 floats = 1536 8-float chunks; 12 per thread; one ds_write_b128 each.
    #pragma unroll
    for (int k = 0; k < 12; ++k) {
        const int idx8 = tid + k * 128;
        const float4 f0 = reinterpret_cast<const float4*>(qkv_w)[idx8 * 2];
        const float4 f1 = reinterpret_cast<const float4*>(qkv_w)[idx8 * 2 + 1];
        const int row  = idx8 >> 3;          // 8 chunks per 64-float row
        const int colB = (idx8 & 7) * 16;    // byte offset, 16 B granularity
        *reinterpret_cast<half8*>(reinterpret_cast<char*>(w_lds) + swz(row, colB)) =
            cvt8(f0, f1);
    }

    // ---------------- proj_w B-frags: direct global->reg prefetch (early) ----------------
    half8 pw0[4], pw1[4];
    #pragma unroll
    for (int nt = 0; nt < 4; ++nt) {
        const float* pb = proj_w + (nt * 16 + lr) * 64 + lg * 8;
        pw0[nt] = cvt8(*reinterpret_cast<const float4*>(pb),
                       *reinterpret_cast<const float4*>(pb + 4));
        pw1[nt] = cvt8(*reinterpret_cast<const float4*>(pb + 32),
                       *reinterpret_cast<const float4*>(pb + 36));
    }

    // ---------------- bias prefetch ----------------
    float bq[12], pbv[4];
    #pragma unroll
    for (int nt = 0; nt < 12; ++nt) bq[nt] = qkv_b[nt * 16 + lr];
    #pragma unroll
    for (int nt = 0; nt < 4; ++nt)  pbv[nt] = proj_b[nt * 16 + lr];

    // ---------------- InstanceNorm in fragment layout ----------------
    float s1 = (x0a.x + x0a.y) + (x0a.z + x0a.w) + (x0b.x + x0b.y) + (x0b.z + x0b.w)
             + (x1a.x + x1a.y) + (x1a.z + x1a.w) + (x1b.x + x1b.y) + (x1b.z + x1b.w);
    float s2 = x0a.x*x0a.x + x0a.y*x0a.y + x0a.z*x0a.z + x0a.w*x0a.w
             + x0b.x*x0b.x + x0b.y*x0b.y + x0b.z*x0b.z + x0b.w*x0b.w
             + x1a.x*x1a.x + x1a.y*x1a.y + x1a.z*x1a.z + x1a.w*x1a.w
             + x1b.x*x1b.x + x1b.y*x1b.y + x1b.z*x1b.z + x1b.w*x1b.w;
    // rows {2g,2g+1} = lr xor 1; k-groups = lane xor 16, 32 -> the instance's 128 values
    s1 += __shfl_xor(s1, 1);  s2 += __shfl_xor(s2, 1);
    s1 += __shfl_xor(s1, 16); s2 += __shfl_xor(s2, 16);
    s1 += __shfl_xor(s1, 32); s2 += __shfl_xor(s2, 32);
    const float mean = s1 * (1.0f / 128.0f);
    const float var  = s2 * (1.0f / 128.0f) - mean * mean;   // biased, like jnp.var
    const float rs   = rsqrtf(var + EPS);

    half8 a0, a1;
    a0[0]=(_Float16)((x0a.x-mean)*rs); a0[1]=(_Float16)((x0a.y-mean)*rs);
    a0[2]=(_Float16)((x0a.z-mean)*rs); a0[3]=(_Float16)((x0a.w-mean)*rs);
    a0[4]=(_Float16)((x0b.x-mean)*rs); a0[5]=(_Float16)((x0b.y-mean)*rs);
    a0[6]=(_Float16)((x0b.z-mean)*rs); a0[7]=(_Float16)((x0b.w-mean)*rs);
    a1[0]=(_Float16)((x1a.x-mean)*rs); a1[1]=(_Float16)((x1a.y-mean)*rs);
    a1[2]=(_Float16)((x1a.z-mean)*rs); a1[3]=(_Float16)((x1a.w-mean)*rs);
    a1[4]=(_Float16)((x1b.x-mean)*rs); a1[5]=(_Float16)((x1b.y-mean)*rs);
    a1[6]=(_Float16)((x1b.z-mean)*rs); a1[7]=(_Float16)((x1b.w-mean)*rs);

    __syncthreads();

    // ---------------- GEMM1: 12 N-tiles x 2 k-steps from swizzled LDS ----------------
    f32x4 acc[12];
    #pragma unroll
    for (int nt = 0; nt < 12; ++nt) acc[nt] = f32x4{0.f, 0.f, 0.f, 0.f};
    #pragma unroll
    for (int nt = 0; nt < 12; ++nt) {
        const int o = nt * 16 + lr;          // weight row = output column
        const half8 b0 = *reinterpret_cast<const half8*>(
            reinterpret_cast<const char*>(w_lds) + swz(o, lg * 16));
        const half8 b1 = *reinterpret_cast<const half8*>(
            reinterpret_cast<const char*>(w_lds) + swz(o, lg * 16 + 64));
        acc[nt] = __builtin_amdgcn_mfma_f32_16x16x32_f16(a0, b0, acc[nt], 0, 0, 0);
        acc[nt] = __builtin_amdgcn_mfma_f32_16x16x32_f16(a1, b1, acc[nt], 0, 0, 0);
    }
    #pragma unroll
    for (int nt = 0; nt < 12; ++nt) {
        acc[nt].x += bq[nt]; acc[nt].y += bq[nt]; acc[nt].z += bq[nt]; acc[nt].w += bq[nt];
    }

    // ---------------- 2x2 M per instance + attn (C-layout registers) ----------------
    // lane holds cols o=nt*16+lr of rows m = w*16 + lg*4 + r; r{0,1}=inst A, r{2,3}=inst B
    float p[8] = {0.f,0.f,0.f,0.f,0.f,0.f,0.f,0.f};
    #pragma unroll
    for (int nt = 0; nt < 4; ++nt) {
        const f32x4 q = acc[nt], k = acc[4 + nt];
        p[0] = fmaf(q.x, k.x, p[0]);  p[1] = fmaf(q.x, k.y, p[1]);
        p[2] = fmaf(q.y, k.x, p[2]);  p[3] = fmaf(q.y, k.y, p[3]);
        p[4] = fmaf(q.z, k.z, p[4]);  p[5] = fmaf(q.z, k.w, p[5]);
        p[6] = fmaf(q.w, k.z, p[6]);  p[7] = fmaf(q.w, k.w, p[7]);
    }
    #pragma unroll
    for (int m = 8; m >= 1; m >>= 1) {    // reduce 64 cols: 16 lanes (lr) x 4 nt
        #pragma unroll
        for (int z = 0; z < 8; ++z) p[z] += __shfl_xor(p[z], m);
    }
    #pragma unroll
    for (int nt = 0; nt < 4; ++nt) {
        const f32x4 v = acc[8 + nt];
        float av[4];
        av[0] = v.x + fmaf(p[0], v.x, p[1] * v.y);
        av[1] = v.y + fmaf(p[2], v.x, p[3] * v.y);
        av[2] = v.z + fmaf(p[4], v.z, p[5] * v.w);
        av[3] = v.w + fmaf(p[6], v.z, p[7] * v.w);
        #pragma unroll
        for (int r = 0; r < 4; ++r) {
            const int row  = (w << 4) + lg * 4 + r;
            const int colB = (nt * 16 + lr) * 2;
            *reinterpret_cast<_Float16*>(
                reinterpret_cast<char*>(a_lds) + swz(row, colB)) = (_Float16)av[r];
        }
    }
    __syncthreads();

    // ---------------- GEMM2: attn @ proj^T (B-frags in regs) ----------------
    const half8 a20 = *reinterpret_cast<const half8*>(
        reinterpret_cast<const char*>(a_lds) + swz(lrow, lg * 16));
    const half8 a21 = *reinterpret_cast<const half8*>(
        reinterpret_cast<const char*>(a_lds) + swz(lrow, lg * 16 + 64));
    f32x4 acc2[4];
    #pragma unroll
    for (int nt = 0; nt < 4; ++nt) acc2[nt] = f32x4{0.f, 0.f, 0.f, 0.f};
    #pragma unroll
    for (int nt = 0; nt < 4; ++nt) {
        acc2[nt] = __builtin_amdgcn_mfma_f32_16x16x32_f16(a20, pw0[nt], acc2[nt], 0, 0, 0);
        acc2[nt] = __builtin_amdgcn_mfma_f32_16x16x32_f16(a21, pw1[nt], acc2[nt], 0, 0, 0);
    }

    // ---------------- epilogue: + proj_b + residual, fp32 store ----------------
    #pragma unroll
    for (int nt = 0; nt < 4; ++nt) {
        const int col = nt * 16 + lr;
        #pragma unroll
        for (int r = 0; r < 4; ++r) {
            const int Rg = blockIdx.x * 32 + (w << 4) + lg * 4 + r;
            const int gi = Rg >> 1, cc = Rg & 1;
            const int nn = gi >> 7, ss = gi & 127;
            const int addr = nn * 16384 + cc * 8192 + ss * 64 + col;
            const float a = (r == 0) ? acc2[nt].x : (r == 1) ? acc2[nt].y
                          : (r == 2) ? acc2[nt].z : acc2[nt].w;
            out[addr] = a + pbv[nt] + inp[addr];
        }
    }
}

extern "C" void kernel_launch(void* const* d_in, const int* in_sizes, int n_in,
                              void* d_out, int out_size, void* d_ws, size_t ws_size,
                              hipStream_t stream) {
    const float* inp    = (const float*)d_in[0];
    const float* qkv_w  = (const float*)d_in[1];
    const float* qkv_b  = (const float*)d_in[2];
    const float* proj_w = (const float*)d_in[3];
    const float* proj_b = (const float*)d_in[4];
    float* out = (float*)d_out;

    // 6400 rows / 32 per block = 200 blocks x 128 threads (2 waves)
    attn_mfma<<<dim3(200), dim3(128), 0, stream>>>(inp, qkv_w, qkv_b, proj_w, proj_b, out);
}